// Round 1
// baseline (380.652 us; speedup 1.0000x reference)
//
#include <hip/hip_runtime.h>
#include <hip/hip_bf16.h>

#define NS 8192
#define NF 45
#define ED 256
#define L1K 11520   // 45*256
#define NH 32

typedef __attribute__((ext_vector_type(8))) short bf16x8;
typedef __attribute__((ext_vector_type(4))) float f32x4;
typedef __attribute__((ext_vector_type(4))) unsigned uint32x4;

// PERM / FIELD_OFF precomputed from SECTIONS/FEATURE_SIZES
__constant__ int c_perm[NF] = {
    0,1,2,3,4,5,6,7,8,9,
    10,11,12,13,14,15,16,17,18,19,20,21,22,23,
    26,27, 28,29, 24,25,
    30,31,32,33,34,35,36,37,38,39,40,41,42,43,44};
__constant__ int c_foff[NF] = {
    0,300,1300,2300,2800,2950,2962,2993,2993,2993,
    3023,3023,3023,3023,3023,3023,3023,3023,3023,3023,3023,3023,3023,3023,
    3223,3223, 53223,53223, 103223,103223,
    123223,123223,123223,123223,123223,123223,123223,123223,
    123223,123223,123223,123223,123223,123223,123223};

__device__ __forceinline__ short f2bf(float x) {
    unsigned u = __builtin_bit_cast(unsigned, x);
    u += 0x7fffu + ((u >> 16) & 1u);   // round-to-nearest-even
    return (short)(u >> 16);
}

// packed f32x2 -> bf16x2 (RNE), single instruction on gfx950
__device__ __forceinline__ unsigned pk_bf16(float a, float b) {
    unsigned r;
    asm("v_cvt_pk_bf16_f32 %0, %1, %2" : "=v"(r) : "v"(a), "v"(b));
    return r;
}

// ---------------- kernel 0: pack l1_w into bf16 B-fragment layout --------
// BFRAG[((f*8+ks)*2+nt)*512 + l*8 + i] = bf16( l1w[nt*16+(l&15)][f*256+ks*32+(l>>4)*8+i] )
__global__ __launch_bounds__(256) void k_pack(const float* __restrict__ l1w,
                                              short* __restrict__ bfrag) {
    int t = blockIdx.x * 256 + threadIdx.x;
    if (t >= NF * 8192) return;
    int i  = t & 7;
    int l  = (t >> 3) & 63;
    int nt = (t >> 9) & 1;
    int ks = (t >> 10) & 7;
    int f  = t >> 13;
    int kout = nt * 16 + (l & 15);
    int col  = f * 256 + ks * 32 + (l >> 4) * 8 + i;
    bfrag[t] = f2bf(l1w[kout * L1K + col]);
}

// ---------------- kernel 1: fused gather + FM + deep GEMM ----------------
// 1024 blocks x 256 thr. Block pair (bx>>1) owns 16 samples; half = bx&1
// covers 128 embed dims; each of 4 waves covers one 32-dim MFMA k-step.
// 3-stage statically-rotated pipeline: ~3 features (~6KB) of W2 gather in
// flight per wave (depth-1 kept only ~2KB outstanding -> ~3.5 TB/s by
// Little's law; this is the MLP fix). __launch_bounds__(256,4) pins
// VGPR<=128 so 4 waves/SIMD stay resident.
__global__ __launch_bounds__(256, 4) void k_main(const float* __restrict__ W2,
                                                 const float* __restrict__ W1,
                                                 const int* __restrict__ Xi,
                                                 const float* __restrict__ Xv,
                                                 const short* __restrict__ bfrag,
                                                 float* __restrict__ h1h,     // [2][NS][NH]
                                                 float* __restrict__ parth) { // [2][NS]
    __shared__ int   s_idx[16 * NF];
    __shared__ float s_xv [16 * NF];
    __shared__ float s_red[4 * 16 * NH];   // 8 KB wave partials of h1pre
    __shared__ float s_q[4][16];
    __shared__ float s_fm1[16];

    const int tid  = threadIdx.x;
    const int w    = tid >> 6;
    const int l    = tid & 63;
    const int m    = l & 15;       // sample-local (MFMA M index)
    const int g4   = l >> 4;       // k-quad within fragment
    const int half = blockIdx.x & 1;
    const int n0   = (blockIdx.x >> 1) * 16;
    const int ks   = half * 4 + w; // this wave's MFMA k-step (0..7)

    for (int t = tid; t < 16 * NF; t += 256) {
        int f = t % NF;
        int n = n0 + t / NF;
        int col = c_perm[f];
        s_idx[t] = Xi[n * NF + col] + c_foff[f];
        s_xv[t]  = Xv[n * NF + col];
    }
    __syncthreads();

    f32x4 acc0 = {0.f, 0.f, 0.f, 0.f};
    f32x4 acc1 = {0.f, 0.f, 0.f, 0.f};
    float sA[8];
    #pragma unroll
    for (int i = 0; i < 8; ++i) sA[i] = 0.f;
    float esq = 0.f, fm1 = 0.f;

    const short* bbase = bfrag + (size_t)ks * 1024 + l * 8;
    const float* wbase = W2 + ks * 32 + g4 * 8;
    const bool  isw0   = (half == 0 && w == 0);
    const int   mNF    = m * NF;

#define LOADF(ff, A0, A1, B0, B1, XV, W1R)                          \
    do {                                                            \
        int idx_ = s_idx[mNF + (ff)];                               \
        XV = s_xv[mNF + (ff)];                                      \
        const float* wr_ = wbase + (size_t)idx_ * ED;               \
        A0 = *(const f32x4*)(wr_);                                  \
        A1 = *(const f32x4*)(wr_ + 4);                              \
        const short* bp_ = bbase + (size_t)(ff) * 8192;             \
        B0 = *(const bf16x8*)(bp_);                                 \
        B1 = *(const bf16x8*)(bp_ + 512);                           \
        W1R = isw0 ? W1[idx_] : 0.f;                                \
    } while (0)

#define COMPF(A0, A1, B0, B1, XV, W1R)                              \
    do {                                                            \
        float e0 = A0.x * XV, e1 = A0.y * XV, e2 = A0.z * XV, e3 = A0.w * XV; \
        float e4 = A1.x * XV, e5 = A1.y * XV, e6 = A1.z * XV, e7 = A1.w * XV; \
        sA[0] += e0; sA[1] += e1; sA[2] += e2; sA[3] += e3;         \
        sA[4] += e4; sA[5] += e5; sA[6] += e6; sA[7] += e7;         \
        esq += e0 * e0; esq += e1 * e1; esq += e2 * e2; esq += e3 * e3; \
        esq += e4 * e4; esq += e5 * e5; esq += e6 * e6; esq += e7 * e7; \
        uint32x4 au_;                                               \
        au_.x = pk_bf16(e0, e1);                                    \
        au_.y = pk_bf16(e2, e3);                                    \
        au_.z = pk_bf16(e4, e5);                                    \
        au_.w = pk_bf16(e6, e7);                                    \
        bf16x8 Af_ = __builtin_bit_cast(bf16x8, au_);               \
        acc0 = __builtin_amdgcn_mfma_f32_16x16x32_bf16(Af_, B0, acc0, 0, 0, 0); \
        acc1 = __builtin_amdgcn_mfma_f32_16x16x32_bf16(Af_, B1, acc1, 0, 0, 0); \
        fm1 += W1R * XV;                                            \
    } while (0)

    f32x4  A0a, A1a, A0b, A1b, A0c, A1c;
    bf16x8 B0a, B1a, B0b, B1b, B0c, B1c;
    float  XVa, XVb, XVc, W1a, W1b, W1c;

    // prologue: fill all 3 stages
    LOADF(0, A0a, A1a, B0a, B1a, XVa, W1a);
    LOADF(1, A0b, A1b, B0b, B1b, XVb, W1b);
    LOADF(2, A0c, A1c, B0c, B1c, XVc, W1c);

    // 14 branch-free iterations: compute f..f+2, refill with f+3..f+5
    for (int f = 0; f < NF - 3; f += 3) {
        COMPF(A0a, A1a, B0a, B1a, XVa, W1a);
        LOADF(f + 3, A0a, A1a, B0a, B1a, XVa, W1a);
        COMPF(A0b, A1b, B0b, B1b, XVb, W1b);
        LOADF(f + 4, A0b, A1b, B0b, B1b, XVb, W1b);
        COMPF(A0c, A1c, B0c, B1c, XVc, W1c);
        LOADF(f + 5, A0c, A1c, B0c, B1c, XVc, W1c);
    }
    // epilogue: drain stages (features 42,43,44)
    COMPF(A0a, A1a, B0a, B1a, XVa, W1a);
    COMPF(A0b, A1b, B0b, B1b, XVb, W1b);
    COMPF(A0c, A1c, B0c, B1c, XVc, W1c);

#undef LOADF
#undef COMPF

    // fm2 partial over this block's 128 j's: sum(sA^2) - sum(e^2)
    float q = -esq;
    #pragma unroll
    for (int i = 0; i < 8; ++i) q += sA[i] * sA[i];
    q += __shfl_xor(q, 16);
    q += __shfl_xor(q, 32);
    if (l < 16) s_q[w][l] = q;
    if (w == 0 && l < 16) s_fm1[l] = fm1;   // zero for half==1

    // stash wave-partial h1pre (D layout: sample=(l>>4)*4+r, j=l&15 [+16 for acc1])
    #pragma unroll
    for (int r = 0; r < 4; ++r) {
        s_red[w * 512 + (g4 * 4 + r) * 32 +      m] = acc0[r];
        s_red[w * 512 + (g4 * 4 + r) * 32 + 16 + m] = acc1[r];
    }
    __syncthreads();

    float* h1out = h1h + (size_t)half * NS * NH;
    for (int t = tid; t < 512; t += 256) {
        float v = s_red[t] + s_red[512 + t] + s_red[1024 + t] + s_red[1536 + t];
        h1out[(size_t)n0 * NH + t] = v;   // t = s*32 + k, contiguous
    }
    if (tid < 16) {
        float fm2 = 0.5f * (s_q[0][tid] + s_q[1][tid] + s_q[2][tid] + s_q[3][tid]);
        parth[half * NS + n0 + tid] = s_fm1[tid] + fm2;
    }
}

// ---------------- kernel 2: S1[32], S2[32][32] over the batch ------------
// 128 blocks x 64 samples (was 64x128): halves the serial per-thread loop.
__global__ __launch_bounds__(256) void k_stats(const float* __restrict__ h1h,
                                               float* __restrict__ S1,
                                               float* __restrict__ S2) {
    __shared__ float hc[64 * NH];   // 8 KB
    const int tid = threadIdx.x;
    const int base = blockIdx.x * 64;   // 128 blocks
    for (int t = tid; t < 64 * NH; t += 256)
        hc[t] = h1h[(size_t)base * NH + t] + h1h[(size_t)NS * NH + base * NH + t];
    __syncthreads();

    const int j = tid >> 3;
    const int ks = (tid & 7) * 4;
    float a0 = 0.f, a1 = 0.f, a2 = 0.f, a3 = 0.f;
    for (int n = 0; n < 64; ++n) {
        float hj = hc[n * NH + j];
        f32x4 h = *(const f32x4*)&hc[n * NH + ks];
        a0 += hj * h.x; a1 += hj * h.y; a2 += hj * h.z; a3 += hj * h.w;
    }
    atomicAdd(&S2[j * NH + ks + 0], a0);
    atomicAdd(&S2[j * NH + ks + 1], a1);
    atomicAdd(&S2[j * NH + ks + 2], a2);
    atomicAdd(&S2[j * NH + ks + 3], a3);
    if (tid < NH) {
        float s = 0.f;
        for (int n = 0; n < 64; ++n) s += hc[n * NH + tid];
        atomicAdd(&S1[tid], s);
    }
}

// ---------------- kernel 3: analytic BN folding -> c[32], K0 -------------
__global__ __launch_bounds__(256) void k_coef(const float* __restrict__ S1,
                                              const float* __restrict__ S2,
                                              const float* __restrict__ g1,
                                              const float* __restrict__ l2w,
                                              const float* __restrict__ g2,
                                              const float* __restrict__ b2,
                                              const float* __restrict__ bias,
                                              float* __restrict__ cvec,
                                              float* __restrict__ k0out) {
    __shared__ float m1[NH], d1[NH], g2r2[NH], csh[NH];
    __shared__ float s2s[NH * NH];   // cache S2 in LDS (was 32x1024 global reads)
    const int t = threadIdx.x;
    const float invN = 1.f / (float)NS;
    for (int i = t; i < NH * NH; i += 256) s2s[i] = S2[i];
    __syncthreads();
    if (t < NH) {
        float mm = S1[t] * invN;
        float v1 = s2s[t * NH + t] * invN - mm * mm;
        m1[t] = mm;
        d1[t] = g1[t] * rsqrtf(v1 + 1e-5f);
    }
    __syncthreads();
    if (t < NH) {
        float aw[NH];
        float p = 0.f;
        for (int j = 0; j < NH; ++j) { aw[j] = l2w[t * NH + j] * d1[j]; p += aw[j] * m1[j]; }
        float v2 = 0.f;
        for (int j = 0; j < NH; ++j) {
            float acc = 0.f;
            for (int j2 = 0; j2 < NH; ++j2) acc += aw[j2] * s2s[j * NH + j2];
            v2 += aw[j] * acc;
        }
        v2 = v2 * invN - p * p;
        g2r2[t] = g2[t] * rsqrtf(v2 + 1e-5f);
    }
    __syncthreads();
    if (t < NH) {
        float s = 0.f;
        for (int k = 0; k < NH; ++k) s += g2r2[k] * l2w[k * NH + t];
        float c = d1[t] * s;
        csh[t] = c;
        cvec[t] = c;
    }
    __syncthreads();
    if (t == 0) {
        float k0 = bias[0];
        for (int k = 0; k < NH; ++k) k0 += b2[k];
        for (int j = 0; j < NH; ++j) k0 -= csh[j] * m1[j];
        k0out[0] = k0;
    }
}

// ---------------- kernel 4: finalize -------------------------------------
__global__ __launch_bounds__(256) void k_final(const float* __restrict__ h1h,
                                               const float* __restrict__ parth,
                                               const float* __restrict__ cvec,
                                               const float* __restrict__ k0p,
                                               float* __restrict__ out) {
    __shared__ float c[NH];
    __shared__ float k0s;
    const int t = threadIdx.x;
    if (t < NH) c[t] = cvec[t];
    if (t == 0) k0s = k0p[0];
    __syncthreads();
    const int n = blockIdx.x * 256 + t;
    const f32x4* hp0 = (const f32x4*)(h1h + (size_t)n * NH);
    const f32x4* hp1 = (const f32x4*)(h1h + (size_t)NS * NH + (size_t)n * NH);
    float dot = 0.f;
    #pragma unroll
    for (int q = 0; q < 8; ++q) {
        f32x4 h0 = hp0[q];
        f32x4 h1 = hp1[q];
        dot += (h0.x + h1.x) * c[q * 4]     + (h0.y + h1.y) * c[q * 4 + 1]
             + (h0.z + h1.z) * c[q * 4 + 2] + (h0.w + h1.w) * c[q * 4 + 3];
    }
    out[n] = parth[n] + parth[NS + n] + dot + k0s;
}

extern "C" void kernel_launch(void* const* d_in, const int* in_sizes, int n_in,
                              void* d_out, int out_size, void* d_ws, size_t ws_size,
                              hipStream_t stream) {
    const int*   Xi   = (const int*)  d_in[0];
    const float* Xv   = (const float*)d_in[1];
    const float* W1   = (const float*)d_in[2];
    const float* W2   = (const float*)d_in[3];
    const float* bias = (const float*)d_in[4];
    const float* l1w  = (const float*)d_in[5];
    // d_in[6] = l1_b  (cancels under BN)
    const float* g1   = (const float*)d_in[7];
    // d_in[8] = bn1_b (cancels)
    const float* l2w  = (const float*)d_in[9];
    // d_in[10] = l2_b (cancels)
    const float* g2   = (const float*)d_in[11];
    const float* b2   = (const float*)d_in[12];
    float* out = (float*)d_out;

    char* ws = (char*)d_ws;
    short* bfrag = (short*)ws;                         // 368640 bf16
    float* h1h   = (float*)(ws + (size_t)368640 * 2);  // 2*8192*32 f
    float* parth = h1h + (size_t)2 * NS * NH;          // 2*8192 f
    float* S1    = parth + 2 * NS;                     // 32
    float* S2    = S1 + NH;                            // 1024
    float* cvec  = S2 + NH * NH;                       // 32
    float* k0p   = cvec + NH;                          // 1

    hipMemsetAsync(S1, 0, (NH + NH * NH) * sizeof(float), stream);
    k_pack <<<(NF * 8192 + 255) / 256, 256, 0, stream>>>(l1w, bfrag);
    k_main <<<NS / 16 * 2, 256, 0, stream>>>(W2, W1, Xi, Xv, bfrag, h1h, parth);
    k_stats<<<128, 256, 0, stream>>>(h1h, S1, S2);
    k_coef <<<1, 256, 0, stream>>>(S1, S2, g1, l2w, g2, b2, bias, cvec, k0p);
    k_final<<<NS / 256, 256, 0, stream>>>(h1h, parth, cvec, k0p, out);
}

// Round 2
// 368.570 us; speedup vs baseline: 1.0328x; 1.0328x over previous
//
#include <hip/hip_runtime.h>
#include <hip/hip_bf16.h>

#define NS 8192
#define NF 45
#define ED 256
#define L1K 11520   // 45*256
#define NH 32

typedef __attribute__((ext_vector_type(8))) short bf16x8;
typedef __attribute__((ext_vector_type(4))) float f32x4;
typedef __attribute__((ext_vector_type(4))) unsigned uint32x4;

// PERM / FIELD_OFF precomputed from SECTIONS/FEATURE_SIZES
__constant__ int c_perm[NF] = {
    0,1,2,3,4,5,6,7,8,9,
    10,11,12,13,14,15,16,17,18,19,20,21,22,23,
    26,27, 28,29, 24,25,
    30,31,32,33,34,35,36,37,38,39,40,41,42,43,44};
__constant__ int c_foff[NF] = {
    0,300,1300,2300,2800,2950,2962,2993,2993,2993,
    3023,3023,3023,3023,3023,3023,3023,3023,3023,3023,3023,3023,3023,3023,
    3223,3223, 53223,53223, 103223,103223,
    123223,123223,123223,123223,123223,123223,123223,123223,
    123223,123223,123223,123223,123223,123223,123223};

__device__ __forceinline__ short f2bf(float x) {
    unsigned u = __builtin_bit_cast(unsigned, x);
    u += 0x7fffu + ((u >> 16) & 1u);   // round-to-nearest-even
    return (short)(u >> 16);
}

// packed f32x2 -> bf16x2 (RNE), single instruction on gfx950
__device__ __forceinline__ unsigned pk_bf16(float a, float b) {
    unsigned r;
    asm("v_cvt_pk_bf16_f32 %0, %1, %2" : "=v"(r) : "v"(a), "v"(b));
    return r;
}

// ---------------- kernel 0: pack l1_w into bf16 B-fragment layout --------
// BFRAG[((f*8+ks)*2+nt)*512 + l*8 + i] = bf16( l1w[nt*16+(l&15)][f*256+ks*32+(l>>4)*8+i] )
__global__ __launch_bounds__(256) void k_pack(const float* __restrict__ l1w,
                                              short* __restrict__ bfrag) {
    int t = blockIdx.x * 256 + threadIdx.x;
    if (t >= NF * 8192) return;
    int i  = t & 7;
    int l  = (t >> 3) & 63;
    int nt = (t >> 9) & 1;
    int ks = (t >> 10) & 7;
    int f  = t >> 13;
    int kout = nt * 16 + (l & 15);
    int col  = f * 256 + ks * 32 + (l >> 4) * 8 + i;
    bfrag[t] = f2bf(l1w[kout * L1K + col]);
}

// ---------------- kernel 1: fused gather + FM + deep GEMM ----------------
// 256 blocks x 512 thr (8 waves). Block owns 32 samples, full 256 embed
// dims; wave w covers k-step ks=w. Each wave processes TWO M=16 sample
// groups sharing the same B fragments -> bfrag L1/L2 traffic halves vs
// the 16-sample/wave layout (369->184 MB/iter). Single h1h copy.
// Depth-3 static pipeline compensates the 4->2 waves/SIMD TLP drop.
__global__ __launch_bounds__(512, 2) void k_main(const float* __restrict__ W2,
                                                 const float* __restrict__ W1,
                                                 const int* __restrict__ Xi,
                                                 const float* __restrict__ Xv,
                                                 const short* __restrict__ bfrag,
                                                 float* __restrict__ h1h,     // [NS][NH]
                                                 float* __restrict__ parth) { // [NS]
    __shared__ int   s_idx[32 * NF];
    __shared__ float s_xv [32 * NF];
    __shared__ float s_red[8 * 32 * 33];   // 33 KB, +1 pad per 32-row
    __shared__ float s_q[8 * 32];
    __shared__ float s_fm1[32];

    const int tid = threadIdx.x;
    const int w   = tid >> 6;      // 0..7 = this wave's MFMA k-step
    const int l   = tid & 63;
    const int m   = l & 15;        // sample-local (MFMA M index)
    const int g4  = l >> 4;        // k-quad within fragment
    const int n0  = blockIdx.x * 32;

    for (int t = tid; t < 32 * NF; t += 512) {
        int f = t % NF;
        int n = n0 + t / NF;
        int col = c_perm[f];
        s_idx[t] = Xi[n * NF + col] + c_foff[f];
        s_xv[t]  = Xv[n * NF + col];
    }
    __syncthreads();

    f32x4 acc00 = {0.f,0.f,0.f,0.f}, acc01 = {0.f,0.f,0.f,0.f};  // samples m,   j 0-15 / 16-31
    f32x4 acc10 = {0.f,0.f,0.f,0.f}, acc11 = {0.f,0.f,0.f,0.f};  // samples 16+m
    float sA0[8], sA1[8];
    #pragma unroll
    for (int i = 0; i < 8; ++i) { sA0[i] = 0.f; sA1[i] = 0.f; }
    float esq0 = 0.f, esq1 = 0.f, fm10 = 0.f, fm11 = 0.f;

    const short* bbase = bfrag + (size_t)w * 1024 + l * 8;
    const float* wbase = W2 + w * 32 + g4 * 8;
    const bool  isw0   = (w == 0);
    const int   mNF    = m * NF;
    const int   mNF1   = (m + 16) * NF;

#define LOADF(ff, A00_,A01_,A10_,A11_,B0_,B1_,XV0_,XV1_,W10_,W11_)  \
    do {                                                            \
        int i0_ = s_idx[mNF  + (ff)];                               \
        int i1_ = s_idx[mNF1 + (ff)];                               \
        XV0_ = s_xv[mNF  + (ff)];                                   \
        XV1_ = s_xv[mNF1 + (ff)];                                   \
        const float* p0_ = wbase + (size_t)i0_ * ED;                \
        const float* p1_ = wbase + (size_t)i1_ * ED;                \
        A00_ = *(const f32x4*)(p0_);  A01_ = *(const f32x4*)(p0_ + 4); \
        A10_ = *(const f32x4*)(p1_);  A11_ = *(const f32x4*)(p1_ + 4); \
        const short* bp_ = bbase + (size_t)(ff) * 8192;             \
        B0_ = *(const bf16x8*)(bp_);                                \
        B1_ = *(const bf16x8*)(bp_ + 512);                          \
        W10_ = isw0 ? W1[i0_] : 0.f;                                \
        W11_ = isw0 ? W1[i1_] : 0.f;                                \
    } while (0)

#define COMPG(A0_,A1_,B0_,B1_,XV_,SA_,ESQ_,ACC0_,ACC1_,FM_,W1R_)    \
    do {                                                            \
        float e0=A0_.x*XV_, e1=A0_.y*XV_, e2=A0_.z*XV_, e3=A0_.w*XV_; \
        float e4=A1_.x*XV_, e5=A1_.y*XV_, e6=A1_.z*XV_, e7=A1_.w*XV_; \
        SA_[0]+=e0; SA_[1]+=e1; SA_[2]+=e2; SA_[3]+=e3;             \
        SA_[4]+=e4; SA_[5]+=e5; SA_[6]+=e6; SA_[7]+=e7;             \
        ESQ_ += e0*e0; ESQ_ += e1*e1; ESQ_ += e2*e2; ESQ_ += e3*e3; \
        ESQ_ += e4*e4; ESQ_ += e5*e5; ESQ_ += e6*e6; ESQ_ += e7*e7; \
        uint32x4 au_;                                               \
        au_.x = pk_bf16(e0,e1);  au_.y = pk_bf16(e2,e3);            \
        au_.z = pk_bf16(e4,e5);  au_.w = pk_bf16(e6,e7);            \
        bf16x8 Af_ = __builtin_bit_cast(bf16x8, au_);               \
        ACC0_ = __builtin_amdgcn_mfma_f32_16x16x32_bf16(Af_, B0_, ACC0_, 0,0,0); \
        ACC1_ = __builtin_amdgcn_mfma_f32_16x16x32_bf16(Af_, B1_, ACC1_, 0,0,0); \
        FM_ += W1R_ * XV_;                                          \
    } while (0)

#define COMPF(A00_,A01_,A10_,A11_,B0_,B1_,XV0_,XV1_,W10_,W11_)      \
    do {                                                            \
        COMPG(A00_,A01_,B0_,B1_,XV0_,sA0,esq0,acc00,acc01,fm10,W10_); \
        COMPG(A10_,A11_,B0_,B1_,XV1_,sA1,esq1,acc10,acc11,fm11,W11_); \
    } while (0)

    f32x4  A00a,A01a,A10a,A11a, A00b,A01b,A10b,A11b, A00c,A01c,A10c,A11c;
    bf16x8 B0a,B1a, B0b,B1b, B0c,B1c;
    float  XV0a,XV1a, XV0b,XV1b, XV0c,XV1c;
    float  W10a,W11a, W10b,W11b, W10c,W11c;

    LOADF(0, A00a,A01a,A10a,A11a,B0a,B1a,XV0a,XV1a,W10a,W11a);
    LOADF(1, A00b,A01b,A10b,A11b,B0b,B1b,XV0b,XV1b,W10b,W11b);
    LOADF(2, A00c,A01c,A10c,A11c,B0c,B1c,XV0c,XV1c,W10c,W11c);

    for (int f = 0; f + 5 < NF; f += 3) {   // f = 0,3,...,39
        COMPF(A00a,A01a,A10a,A11a,B0a,B1a,XV0a,XV1a,W10a,W11a);
        LOADF(f + 3, A00a,A01a,A10a,A11a,B0a,B1a,XV0a,XV1a,W10a,W11a);
        COMPF(A00b,A01b,A10b,A11b,B0b,B1b,XV0b,XV1b,W10b,W11b);
        LOADF(f + 4, A00b,A01b,A10b,A11b,B0b,B1b,XV0b,XV1b,W10b,W11b);
        COMPF(A00c,A01c,A10c,A11c,B0c,B1c,XV0c,XV1c,W10c,W11c);
        LOADF(f + 5, A00c,A01c,A10c,A11c,B0c,B1c,XV0c,XV1c,W10c,W11c);
    }
    // stages hold f = 42(a), 43(b), 44 still unloaded -> load into c slot? no:
    // loop consumed through f=41, loaded through 44? recount: last iter f=39
    // loaded 42,43,44 into a,b,c. Drain all three.
    COMPF(A00a,A01a,A10a,A11a,B0a,B1a,XV0a,XV1a,W10a,W11a);
    COMPF(A00b,A01b,A10b,A11b,B0b,B1b,XV0b,XV1b,W10b,W11b);
    COMPF(A00c,A01c,A10c,A11c,B0c,B1c,XV0c,XV1c,W10c,W11c);

#undef LOADF
#undef COMPG
#undef COMPF

    // fm2 wave-partials: q = sum(sA^2) - sum(e^2) over this wave's 32 dims
    float q0 = -esq0, q1 = -esq1;
    #pragma unroll
    for (int i = 0; i < 8; ++i) { q0 += sA0[i] * sA0[i]; q1 += sA1[i] * sA1[i]; }
    q0 += __shfl_xor(q0, 16);  q0 += __shfl_xor(q0, 32);
    q1 += __shfl_xor(q1, 16);  q1 += __shfl_xor(q1, 32);
    if (l < 16) {
        s_q[w * 32 + m]      = q0;
        s_q[w * 32 + 16 + m] = q1;
        if (w == 0) { s_fm1[m] = fm10; s_fm1[16 + m] = fm11; }
    }

    // stash wave-partial h1pre: row = sample (0..31), col = j (0..31)
    #pragma unroll
    for (int r = 0; r < 4; ++r) {
        s_red[w * 1056 + (g4 * 4 + r) * 33 +      m] = acc00[r];
        s_red[w * 1056 + (g4 * 4 + r) * 33 + 16 + m] = acc01[r];
        s_red[w * 1056 + (16 + g4 * 4 + r) * 33 +      m] = acc10[r];
        s_red[w * 1056 + (16 + g4 * 4 + r) * 33 + 16 + m] = acc11[r];
    }
    __syncthreads();

    for (int t = tid; t < 1024; t += 512) {
        int s = t >> 5, j = t & 31;
        float v = 0.f;
        #pragma unroll
        for (int ww = 0; ww < 8; ++ww) v += s_red[ww * 1056 + s * 33 + j];
        h1h[(size_t)n0 * NH + t] = v;   // t = s*32 + j, contiguous
    }
    if (tid < 32) {
        float fm2 = 0.f;
        #pragma unroll
        for (int ww = 0; ww < 8; ++ww) fm2 += s_q[ww * 32 + tid];
        parth[n0 + tid] = s_fm1[tid] + 0.5f * fm2;
    }
}

// ---------------- kernel 2: S1[32], S2[32][32] over the batch ------------
__global__ __launch_bounds__(256) void k_stats(const float* __restrict__ h1h,
                                               float* __restrict__ S1,
                                               float* __restrict__ S2) {
    __shared__ float hc[64 * NH];   // 8 KB
    const int tid = threadIdx.x;
    const int base = blockIdx.x * 64;   // 128 blocks
    for (int t = tid; t < 64 * NH; t += 256)
        hc[t] = h1h[(size_t)base * NH + t];
    __syncthreads();

    const int j = tid >> 3;
    const int ks = (tid & 7) * 4;
    float a0 = 0.f, a1 = 0.f, a2 = 0.f, a3 = 0.f;
    for (int n = 0; n < 64; ++n) {
        float hj = hc[n * NH + j];
        f32x4 h = *(const f32x4*)&hc[n * NH + ks];
        a0 += hj * h.x; a1 += hj * h.y; a2 += hj * h.z; a3 += hj * h.w;
    }
    atomicAdd(&S2[j * NH + ks + 0], a0);
    atomicAdd(&S2[j * NH + ks + 1], a1);
    atomicAdd(&S2[j * NH + ks + 2], a2);
    atomicAdd(&S2[j * NH + ks + 3], a3);
    if (tid < NH) {
        float s = 0.f;
        for (int n = 0; n < 64; ++n) s += hc[n * NH + tid];
        atomicAdd(&S1[tid], s);
    }
}

// ---------------- kernel 3: analytic BN folding -> c[32], K0 -------------
__global__ __launch_bounds__(256) void k_coef(const float* __restrict__ S1,
                                              const float* __restrict__ S2,
                                              const float* __restrict__ g1,
                                              const float* __restrict__ l2w,
                                              const float* __restrict__ g2,
                                              const float* __restrict__ b2,
                                              const float* __restrict__ bias,
                                              float* __restrict__ cvec,
                                              float* __restrict__ k0out) {
    __shared__ float m1[NH], d1[NH], g2r2[NH], csh[NH];
    __shared__ float s2s[NH * NH];
    const int t = threadIdx.x;
    const float invN = 1.f / (float)NS;
    for (int i = t; i < NH * NH; i += 256) s2s[i] = S2[i];
    __syncthreads();
    if (t < NH) {
        float mm = S1[t] * invN;
        float v1 = s2s[t * NH + t] * invN - mm * mm;
        m1[t] = mm;
        d1[t] = g1[t] * rsqrtf(v1 + 1e-5f);
    }
    __syncthreads();
    if (t < NH) {
        float aw[NH];
        float p = 0.f;
        for (int j = 0; j < NH; ++j) { aw[j] = l2w[t * NH + j] * d1[j]; p += aw[j] * m1[j]; }
        float v2 = 0.f;
        for (int j = 0; j < NH; ++j) {
            float acc = 0.f;
            for (int j2 = 0; j2 < NH; ++j2) acc += aw[j2] * s2s[j * NH + j2];
            v2 += aw[j] * acc;
        }
        v2 = v2 * invN - p * p;
        g2r2[t] = g2[t] * rsqrtf(v2 + 1e-5f);
    }
    __syncthreads();
    if (t < NH) {
        float s = 0.f;
        for (int k = 0; k < NH; ++k) s += g2r2[k] * l2w[k * NH + t];
        float c = d1[t] * s;
        csh[t] = c;
        cvec[t] = c;
    }
    __syncthreads();
    if (t == 0) {
        float k0 = bias[0];
        for (int k = 0; k < NH; ++k) k0 += b2[k];
        for (int j = 0; j < NH; ++j) k0 -= csh[j] * m1[j];
        k0out[0] = k0;
    }
}

// ---------------- kernel 4: finalize -------------------------------------
__global__ __launch_bounds__(256) void k_final(const float* __restrict__ h1h,
                                               const float* __restrict__ parth,
                                               const float* __restrict__ cvec,
                                               const float* __restrict__ k0p,
                                               float* __restrict__ out) {
    __shared__ float c[NH];
    __shared__ float k0s;
    const int t = threadIdx.x;
    if (t < NH) c[t] = cvec[t];
    if (t == 0) k0s = k0p[0];
    __syncthreads();
    const int n = blockIdx.x * 256 + t;
    const f32x4* hp0 = (const f32x4*)(h1h + (size_t)n * NH);
    float dot = 0.f;
    #pragma unroll
    for (int q = 0; q < 8; ++q) {
        f32x4 h0 = hp0[q];
        dot += h0.x * c[q * 4]     + h0.y * c[q * 4 + 1]
             + h0.z * c[q * 4 + 2] + h0.w * c[q * 4 + 3];
    }
    out[n] = parth[n] + dot + k0s;
}

extern "C" void kernel_launch(void* const* d_in, const int* in_sizes, int n_in,
                              void* d_out, int out_size, void* d_ws, size_t ws_size,
                              hipStream_t stream) {
    const int*   Xi   = (const int*)  d_in[0];
    const float* Xv   = (const float*)d_in[1];
    const float* W1   = (const float*)d_in[2];
    const float* W2   = (const float*)d_in[3];
    const float* bias = (const float*)d_in[4];
    const float* l1w  = (const float*)d_in[5];
    // d_in[6] = l1_b  (cancels under BN)
    const float* g1   = (const float*)d_in[7];
    // d_in[8] = bn1_b (cancels)
    const float* l2w  = (const float*)d_in[9];
    // d_in[10] = l2_b (cancels)
    const float* g2   = (const float*)d_in[11];
    const float* b2   = (const float*)d_in[12];
    float* out = (float*)d_out;

    char* ws = (char*)d_ws;
    short* bfrag = (short*)ws;                         // 368640 bf16
    float* h1h   = (float*)(ws + (size_t)368640 * 2);  // NS*NH f
    float* parth = h1h + (size_t)NS * NH;              // NS f
    float* S1    = parth + NS;                         // 32
    float* S2    = S1 + NH;                            // 1024
    float* cvec  = S2 + NH * NH;                       // 32
    float* k0p   = cvec + NH;                          // 1

    hipMemsetAsync(S1, 0, (NH + NH * NH) * sizeof(float), stream);
    k_pack <<<(NF * 8192 + 255) / 256, 256, 0, stream>>>(l1w, bfrag);
    k_main <<<NS / 32, 512, 0, stream>>>(W2, W1, Xi, Xv, bfrag, h1h, parth);
    k_stats<<<128, 256, 0, stream>>>(h1h, S1, S2);
    k_coef <<<1, 256, 0, stream>>>(S1, S2, g1, l2w, g2, b2, bias, cvec, k0p);
    k_final<<<NS / 256, 256, 0, stream>>>(h1h, parth, cvec, k0p, out);
}

// Round 3
// 363.230 us; speedup vs baseline: 1.0480x; 1.0147x over previous
//
#include <hip/hip_runtime.h>
#include <hip/hip_bf16.h>

#define NS 8192
#define NF 45
#define ED 256
#define L1K 11520   // 45*256
#define NH 32

typedef __attribute__((ext_vector_type(8))) short bf16x8;
typedef __attribute__((ext_vector_type(4))) float f32x4;
typedef __attribute__((ext_vector_type(4))) unsigned uint32x4;

// PERM / FIELD_OFF precomputed from SECTIONS/FEATURE_SIZES
__constant__ int c_perm[NF] = {
    0,1,2,3,4,5,6,7,8,9,
    10,11,12,13,14,15,16,17,18,19,20,21,22,23,
    26,27, 28,29, 24,25,
    30,31,32,33,34,35,36,37,38,39,40,41,42,43,44};
__constant__ int c_foff[NF] = {
    0,300,1300,2300,2800,2950,2962,2993,2993,2993,
    3023,3023,3023,3023,3023,3023,3023,3023,3023,3023,3023,3023,3023,3023,
    3223,3223, 53223,53223, 103223,103223,
    123223,123223,123223,123223,123223,123223,123223,123223,
    123223,123223,123223,123223,123223,123223,123223};

__device__ __forceinline__ short f2bf(float x) {
    unsigned u = __builtin_bit_cast(unsigned, x);
    u += 0x7fffu + ((u >> 16) & 1u);   // round-to-nearest-even
    return (short)(u >> 16);
}

// packed f32x2 -> bf16x2 (RNE), single instruction on gfx950
__device__ __forceinline__ unsigned pk_bf16(float a, float b) {
    unsigned r;
    asm("v_cvt_pk_bf16_f32 %0, %1, %2" : "=v"(r) : "v"(a), "v"(b));
    return r;
}

// ---------------- kernel 0: pack l1_w into bf16 B-fragment layout --------
// BFRAG[((f*8+ks)*2+nt)*512 + l*8 + i] = bf16( l1w[nt*16+(l&15)][f*256+ks*32+(l>>4)*8+i] )
__global__ __launch_bounds__(256) void k_pack(const float* __restrict__ l1w,
                                              short* __restrict__ bfrag) {
    int t = blockIdx.x * 256 + threadIdx.x;
    if (t >= NF * 8192) return;
    int i  = t & 7;
    int l  = (t >> 3) & 63;
    int nt = (t >> 9) & 1;
    int ks = (t >> 10) & 7;
    int f  = t >> 13;
    int kout = nt * 16 + (l & 15);
    int col  = f * 256 + ks * 32 + (l >> 4) * 8 + i;
    bfrag[t] = f2bf(l1w[kout * L1K + col]);
}

// ---------------- kernel 1: fused gather + FM + deep GEMM + stats --------
// 256 blocks x 512 thr (8 waves). Block owns 32 samples, full 256 embed
// dims; wave w covers k-step ks=w; each wave serves TWO M=16 sample groups
// sharing the same B fragments (bfrag traffic halved vs 16-sample waves).
// Depth-4 static pipeline: 8 wave-features in flight per SIMD at
// 2 waves/SIMD (R2's depth-3 was latency-marginal vs ~600-900cy gather).
// Epilogue computes per-block S1/S2 partials from the LDS h-tile and
// atomicAdds them -> k_stats kernel deleted (no 1MB re-read, no launch).
__global__ __launch_bounds__(512, 2) void k_main(const float* __restrict__ W2,
                                                 const float* __restrict__ W1,
                                                 const int* __restrict__ Xi,
                                                 const float* __restrict__ Xv,
                                                 const short* __restrict__ bfrag,
                                                 float* __restrict__ h1h,     // [NS][NH]
                                                 float* __restrict__ parth,   // [NS]
                                                 float* __restrict__ S1,      // [NH]
                                                 float* __restrict__ S2) {    // [NH][NH]
    __shared__ int   s_idx[32 * NF];
    __shared__ float s_xv [32 * NF];
    __shared__ float s_red[8 * 32 * 33];   // 33 KB, +1 pad per 32-row
    __shared__ float s_q[8 * 32];
    __shared__ float s_fm1[32];
    __shared__ float s_h[32 * 33];         // finished h-tile for stats

    const int tid = threadIdx.x;
    const int w   = tid >> 6;      // 0..7 = this wave's MFMA k-step
    const int l   = tid & 63;
    const int m   = l & 15;        // sample-local (MFMA M index)
    const int g4  = l >> 4;        // k-quad within fragment
    const int n0  = blockIdx.x * 32;

    for (int t = tid; t < 32 * NF; t += 512) {
        int f = t % NF;
        int n = n0 + t / NF;
        int col = c_perm[f];
        s_idx[t] = Xi[n * NF + col] + c_foff[f];
        s_xv[t]  = Xv[n * NF + col];
    }
    __syncthreads();

    f32x4 acc00 = {0.f,0.f,0.f,0.f}, acc01 = {0.f,0.f,0.f,0.f};  // samples m,   j 0-15 / 16-31
    f32x4 acc10 = {0.f,0.f,0.f,0.f}, acc11 = {0.f,0.f,0.f,0.f};  // samples 16+m
    float sA0[8], sA1[8];
    #pragma unroll
    for (int i = 0; i < 8; ++i) { sA0[i] = 0.f; sA1[i] = 0.f; }
    float esq0 = 0.f, esq1 = 0.f, fm10 = 0.f, fm11 = 0.f;

    const short* bbase = bfrag + (size_t)w * 1024 + l * 8;
    const float* wbase = W2 + w * 32 + g4 * 8;
    const bool  isw0   = (w == 0);
    const int   mNF    = m * NF;
    const int   mNF1   = (m + 16) * NF;

#define LOADF(ff, A00_,A01_,A10_,A11_,B0_,B1_,XV0_,XV1_,W10_,W11_)  \
    do {                                                            \
        int i0_ = s_idx[mNF  + (ff)];                               \
        int i1_ = s_idx[mNF1 + (ff)];                               \
        XV0_ = s_xv[mNF  + (ff)];                                   \
        XV1_ = s_xv[mNF1 + (ff)];                                   \
        const float* p0_ = wbase + (size_t)i0_ * ED;                \
        const float* p1_ = wbase + (size_t)i1_ * ED;                \
        A00_ = *(const f32x4*)(p0_);  A01_ = *(const f32x4*)(p0_ + 4); \
        A10_ = *(const f32x4*)(p1_);  A11_ = *(const f32x4*)(p1_ + 4); \
        const short* bp_ = bbase + (size_t)(ff) * 8192;             \
        B0_ = *(const bf16x8*)(bp_);                                \
        B1_ = *(const bf16x8*)(bp_ + 512);                          \
        W10_ = isw0 ? W1[i0_] : 0.f;                                \
        W11_ = isw0 ? W1[i1_] : 0.f;                                \
    } while (0)

#define COMPG(A0_,A1_,B0_,B1_,XV_,SA_,ESQ_,ACC0_,ACC1_,FM_,W1R_)    \
    do {                                                            \
        float e0=A0_.x*XV_, e1=A0_.y*XV_, e2=A0_.z*XV_, e3=A0_.w*XV_; \
        float e4=A1_.x*XV_, e5=A1_.y*XV_, e6=A1_.z*XV_, e7=A1_.w*XV_; \
        SA_[0]+=e0; SA_[1]+=e1; SA_[2]+=e2; SA_[3]+=e3;             \
        SA_[4]+=e4; SA_[5]+=e5; SA_[6]+=e6; SA_[7]+=e7;             \
        ESQ_ += e0*e0; ESQ_ += e1*e1; ESQ_ += e2*e2; ESQ_ += e3*e3; \
        ESQ_ += e4*e4; ESQ_ += e5*e5; ESQ_ += e6*e6; ESQ_ += e7*e7; \
        uint32x4 au_;                                               \
        au_.x = pk_bf16(e0,e1);  au_.y = pk_bf16(e2,e3);            \
        au_.z = pk_bf16(e4,e5);  au_.w = pk_bf16(e6,e7);            \
        bf16x8 Af_ = __builtin_bit_cast(bf16x8, au_);               \
        ACC0_ = __builtin_amdgcn_mfma_f32_16x16x32_bf16(Af_, B0_, ACC0_, 0,0,0); \
        ACC1_ = __builtin_amdgcn_mfma_f32_16x16x32_bf16(Af_, B1_, ACC1_, 0,0,0); \
        FM_ += W1R_ * XV_;                                          \
    } while (0)

#define COMPF(A00_,A01_,A10_,A11_,B0_,B1_,XV0_,XV1_,W10_,W11_)      \
    do {                                                            \
        COMPG(A00_,A01_,B0_,B1_,XV0_,sA0,esq0,acc00,acc01,fm10,W10_); \
        COMPG(A10_,A11_,B0_,B1_,XV1_,sA1,esq1,acc10,acc11,fm11,W11_); \
    } while (0)

    f32x4  A00a,A01a,A10a,A11a, A00b,A01b,A10b,A11b;
    f32x4  A00c,A01c,A10c,A11c, A00d,A01d,A10d,A11d;
    bf16x8 B0a,B1a, B0b,B1b, B0c,B1c, B0d,B1d;
    float  XV0a,XV1a, XV0b,XV1b, XV0c,XV1c, XV0d,XV1d;
    float  W10a,W11a, W10b,W11b, W10c,W11c, W10d,W11d;

    LOADF(0, A00a,A01a,A10a,A11a,B0a,B1a,XV0a,XV1a,W10a,W11a);
    LOADF(1, A00b,A01b,A10b,A11b,B0b,B1b,XV0b,XV1b,W10b,W11b);
    LOADF(2, A00c,A01c,A10c,A11c,B0c,B1c,XV0c,XV1c,W10c,W11c);
    LOADF(3, A00d,A01d,A10d,A11d,B0d,B1d,XV0d,XV1d,W10d,W11d);

    for (int f = 0; f + 7 < NF; f += 4) {   // f = 0,4,...,36
        COMPF(A00a,A01a,A10a,A11a,B0a,B1a,XV0a,XV1a,W10a,W11a);
        LOADF(f + 4, A00a,A01a,A10a,A11a,B0a,B1a,XV0a,XV1a,W10a,W11a);
        COMPF(A00b,A01b,A10b,A11b,B0b,B1b,XV0b,XV1b,W10b,W11b);
        LOADF(f + 5, A00b,A01b,A10b,A11b,B0b,B1b,XV0b,XV1b,W10b,W11b);
        COMPF(A00c,A01c,A10c,A11c,B0c,B1c,XV0c,XV1c,W10c,W11c);
        LOADF(f + 6, A00c,A01c,A10c,A11c,B0c,B1c,XV0c,XV1c,W10c,W11c);
        COMPF(A00d,A01d,A10d,A11d,B0d,B1d,XV0d,XV1d,W10d,W11d);
        LOADF(f + 7, A00d,A01d,A10d,A11d,B0d,B1d,XV0d,XV1d,W10d,W11d);
    }
    // after last iter (f=36): consumed 36..39, stages hold 40(a),41(b),42(c),43(d)
    COMPF(A00a,A01a,A10a,A11a,B0a,B1a,XV0a,XV1a,W10a,W11a);            // f=40
    LOADF(44, A00a,A01a,A10a,A11a,B0a,B1a,XV0a,XV1a,W10a,W11a);
    COMPF(A00b,A01b,A10b,A11b,B0b,B1b,XV0b,XV1b,W10b,W11b);            // f=41
    COMPF(A00c,A01c,A10c,A11c,B0c,B1c,XV0c,XV1c,W10c,W11c);            // f=42
    COMPF(A00d,A01d,A10d,A11d,B0d,B1d,XV0d,XV1d,W10d,W11d);            // f=43
    COMPF(A00a,A01a,A10a,A11a,B0a,B1a,XV0a,XV1a,W10a,W11a);            // f=44

#undef LOADF
#undef COMPG
#undef COMPF

    // fm2 wave-partials: q = sum(sA^2) - sum(e^2) over this wave's 32 dims
    float q0 = -esq0, q1 = -esq1;
    #pragma unroll
    for (int i = 0; i < 8; ++i) { q0 += sA0[i] * sA0[i]; q1 += sA1[i] * sA1[i]; }
    q0 += __shfl_xor(q0, 16);  q0 += __shfl_xor(q0, 32);
    q1 += __shfl_xor(q1, 16);  q1 += __shfl_xor(q1, 32);
    if (l < 16) {
        s_q[w * 32 + m]      = q0;
        s_q[w * 32 + 16 + m] = q1;
        if (w == 0) { s_fm1[m] = fm10; s_fm1[16 + m] = fm11; }
    }

    // stash wave-partial h1pre: row = sample (0..31), col = j (0..31)
    #pragma unroll
    for (int r = 0; r < 4; ++r) {
        s_red[w * 1056 + (g4 * 4 + r) * 33 +      m] = acc00[r];
        s_red[w * 1056 + (g4 * 4 + r) * 33 + 16 + m] = acc01[r];
        s_red[w * 1056 + (16 + g4 * 4 + r) * 33 +      m] = acc10[r];
        s_red[w * 1056 + (16 + g4 * 4 + r) * 33 + 16 + m] = acc11[r];
    }
    __syncthreads();

    for (int t = tid; t < 1024; t += 512) {
        int s = t >> 5, j = t & 31;
        float v = 0.f;
        #pragma unroll
        for (int ww = 0; ww < 8; ++ww) v += s_red[ww * 1056 + s * 33 + j];
        h1h[(size_t)n0 * NH + t] = v;   // t = s*32 + j, contiguous
        s_h[s * 33 + j] = v;
    }
    if (tid < 32) {
        float fm2 = 0.f;
        #pragma unroll
        for (int ww = 0; ww < 8; ++ww) fm2 += s_q[ww * 32 + tid];
        parth[n0 + tid] = s_fm1[tid] + 0.5f * fm2;
    }
    __syncthreads();

    // fused stats: block-partial S2 (32x32) and S1 (32) from the LDS tile
    {
        const int j  = tid >> 4;          // 0..31
        const int kk = (tid & 15) << 1;   // 0,2,...,30
        float p0 = 0.f, p1 = 0.f;
        #pragma unroll 8
        for (int s = 0; s < 32; ++s) {
            float hj = s_h[s * 33 + j];
            p0 += hj * s_h[s * 33 + kk];
            p1 += hj * s_h[s * 33 + kk + 1];
        }
        atomicAdd(&S2[j * NH + kk],     p0);
        atomicAdd(&S2[j * NH + kk + 1], p1);
        if (tid < 32) {
            float s1 = 0.f;
            #pragma unroll 8
            for (int s = 0; s < 32; ++s) s1 += s_h[s * 33 + tid];
            atomicAdd(&S1[tid], s1);
        }
    }
}

// ---------------- kernel 3: analytic BN folding -> c[32], K0 -------------
__global__ __launch_bounds__(256) void k_coef(const float* __restrict__ S1,
                                              const float* __restrict__ S2,
                                              const float* __restrict__ g1,
                                              const float* __restrict__ l2w,
                                              const float* __restrict__ g2,
                                              const float* __restrict__ b2,
                                              const float* __restrict__ bias,
                                              float* __restrict__ cvec,
                                              float* __restrict__ k0out) {
    __shared__ float m1[NH], d1[NH], g2r2[NH], csh[NH];
    __shared__ float s2s[NH * NH];
    const int t = threadIdx.x;
    const float invN = 1.f / (float)NS;
    for (int i = t; i < NH * NH; i += 256) s2s[i] = S2[i];
    __syncthreads();
    if (t < NH) {
        float mm = S1[t] * invN;
        float v1 = s2s[t * NH + t] * invN - mm * mm;
        m1[t] = mm;
        d1[t] = g1[t] * rsqrtf(v1 + 1e-5f);
    }
    __syncthreads();
    if (t < NH) {
        float aw[NH];
        float p = 0.f;
        for (int j = 0; j < NH; ++j) { aw[j] = l2w[t * NH + j] * d1[j]; p += aw[j] * m1[j]; }
        float v2 = 0.f;
        for (int j = 0; j < NH; ++j) {
            float acc = 0.f;
            for (int j2 = 0; j2 < NH; ++j2) acc += aw[j2] * s2s[j * NH + j2];
            v2 += aw[j] * acc;
        }
        v2 = v2 * invN - p * p;
        g2r2[t] = g2[t] * rsqrtf(v2 + 1e-5f);
    }
    __syncthreads();
    if (t < NH) {
        float s = 0.f;
        for (int k = 0; k < NH; ++k) s += g2r2[k] * l2w[k * NH + t];
        float c = d1[t] * s;
        csh[t] = c;
        cvec[t] = c;
    }
    __syncthreads();
    if (t == 0) {
        float k0 = bias[0];
        for (int k = 0; k < NH; ++k) k0 += b2[k];
        for (int j = 0; j < NH; ++j) k0 -= csh[j] * m1[j];
        k0out[0] = k0;
    }
}

// ---------------- kernel 4: finalize -------------------------------------
__global__ __launch_bounds__(256) void k_final(const float* __restrict__ h1h,
                                               const float* __restrict__ parth,
                                               const float* __restrict__ cvec,
                                               const float* __restrict__ k0p,
                                               float* __restrict__ out) {
    __shared__ float c[NH];
    __shared__ float k0s;
    const int t = threadIdx.x;
    if (t < NH) c[t] = cvec[t];
    if (t == 0) k0s = k0p[0];
    __syncthreads();
    const int n = blockIdx.x * 256 + t;
    const f32x4* hp0 = (const f32x4*)(h1h + (size_t)n * NH);
    float dot = 0.f;
    #pragma unroll
    for (int q = 0; q < 8; ++q) {
        f32x4 h0 = hp0[q];
        dot += h0.x * c[q * 4]     + h0.y * c[q * 4 + 1]
             + h0.z * c[q * 4 + 2] + h0.w * c[q * 4 + 3];
    }
    out[n] = parth[n] + dot + k0s;
}

extern "C" void kernel_launch(void* const* d_in, const int* in_sizes, int n_in,
                              void* d_out, int out_size, void* d_ws, size_t ws_size,
                              hipStream_t stream) {
    const int*   Xi   = (const int*)  d_in[0];
    const float* Xv   = (const float*)d_in[1];
    const float* W1   = (const float*)d_in[2];
    const float* W2   = (const float*)d_in[3];
    const float* bias = (const float*)d_in[4];
    const float* l1w  = (const float*)d_in[5];
    // d_in[6] = l1_b  (cancels under BN)
    const float* g1   = (const float*)d_in[7];
    // d_in[8] = bn1_b (cancels)
    const float* l2w  = (const float*)d_in[9];
    // d_in[10] = l2_b (cancels)
    const float* g2   = (const float*)d_in[11];
    const float* b2   = (const float*)d_in[12];
    float* out = (float*)d_out;

    char* ws = (char*)d_ws;
    short* bfrag = (short*)ws;                         // 368640 bf16
    float* h1h   = (float*)(ws + (size_t)368640 * 2);  // NS*NH f
    float* parth = h1h + (size_t)NS * NH;              // NS f
    float* S1    = parth + NS;                         // 32
    float* S2    = S1 + NH;                            // 1024
    float* cvec  = S2 + NH * NH;                       // 32
    float* k0p   = cvec + NH;                          // 1

    hipMemsetAsync(S1, 0, (NH + NH * NH) * sizeof(float), stream);
    k_pack <<<(NF * 8192 + 255) / 256, 256, 0, stream>>>(l1w, bfrag);
    k_main <<<NS / 32, 512, 0, stream>>>(W2, W1, Xi, Xv, bfrag, h1h, parth, S1, S2);
    k_coef <<<1, 256, 0, stream>>>(S1, S2, g1, l2w, g2, b2, bias, cvec, k0p);
    k_final<<<NS / 256, 256, 0, stream>>>(h1h, parth, cvec, k0p, out);
}